// Round 16
// baseline (514.467 us; speedup 1.0000x reference)
//
#include <hip/hip_runtime.h>
#include <hip/hip_bf16.h>
#include <hip/hip_cooperative_groups.h>
#include <math.h>

namespace cg = cooperative_groups;

#define BSZ 2
#define LSEQ 2048
#define DMODEL 1024
#define DSTATE 16
#define DCONV 4
#define DINNER 2048
#define DTRANK 64
#define NPROJ (DTRANK + 2 * DSTATE) // 96
#define NC 32   // scan chunks
#define LC 64   // steps per chunk
#define KS 4    // proj split-K chunks
#define KCH (DINNER / KS) // 512

using short8 = __attribute__((ext_vector_type(8))) short;
using f32x4 = __attribute__((ext_vector_type(4))) float;
using u16x4 = __attribute__((ext_vector_type(4))) unsigned short;

__device__ __forceinline__ float silu_f(float v) {
    return v / (1.f + expf(-v));
}
__device__ __forceinline__ float softplus_f(float v) {
    return fmaxf(v, 0.f) + log1pf(expf(-fabsf(v)));
}
// fp32 -> bf16 bits, round-to-nearest-even
__device__ __forceinline__ unsigned short f2bf(float f) {
    unsigned u = __builtin_bit_cast(unsigned, f);
    u += 0x7fffu + ((u >> 16) & 1u);
    return (unsigned short)(u >> 16);
}
__device__ __forceinline__ float bf2f(unsigned short u) {
    unsigned x = ((unsigned)u) << 16;
    return __builtin_bit_cast(float, x);
}

__device__ __forceinline__ void gld_lds16(const unsigned short* g, unsigned short* l) {
    __builtin_amdgcn_global_load_lds(
        (const __attribute__((address_space(1))) unsigned int*)g,
        (__attribute__((address_space(3))) unsigned int*)l, 16, 0, 0);
}

// bijective XCD swizzle (requires nwg % 8 == 0)
__device__ __forceinline__ int xcd_swz(int wg, int nwg) {
    return (wg & 7) * (nwg >> 3) + (wg >> 3);
}

// ---- fused prep: x->bf16 + weight transposes ----
__global__ __launch_bounds__(256) void prep_kernel(
    const float* __restrict__ x, const float* __restrict__ W_in,
    const float* __restrict__ W_out, const float* __restrict__ W_xproj,
    const float* __restrict__ W_dt,
    unsigned short* __restrict__ xbf, unsigned short* __restrict__ WinT,
    unsigned short* __restrict__ WoutT, unsigned short* __restrict__ WxT,
    unsigned short* __restrict__ WdtT) {
    int bid = blockIdx.x;
    if (bid < 4096) { // x -> bf16
        int i = bid * 256 + threadIdx.x;
        float4 v = reinterpret_cast<const float4*>(x)[i];
        u16x4 o = {f2bf(v.x), f2bf(v.y), f2bf(v.z), f2bf(v.w)};
        reinterpret_cast<u16x4*>(xbf)[i] = o;
        return;
    }
    bid -= 4096;
    if (bid < 1024 + 512) { // 64x64 transposes: W_in, W_out
        const float* in;
        unsigned short* outp;
        int R, Cc, gx;
        if (bid < 1024) { in = W_in; outp = WinT; R = 1024; Cc = 4096; gx = 64; }
        else { bid -= 1024; in = W_out; outp = WoutT; R = 2048; Cc = 1024; gx = 16; }
        const int bx = bid % gx, by = bid / gx;
        __shared__ float t64[64][65];
        const int tx = threadIdx.x & 63, ty = threadIdx.x >> 6; // 64 x 4
        const int c0 = bx * 64, r0 = by * 64;
#pragma unroll
        for (int i = 0; i < 16; i++)
            t64[ty + 4 * i][tx] = in[(size_t)(r0 + ty + 4 * i) * Cc + c0 + tx];
        __syncthreads();
#pragma unroll
        for (int i = 0; i < 16; i++) {
            int rr = ty + 4 * i;
            outp[(size_t)(c0 + rr) * R + r0 + tx] = f2bf(t64[tx][rr]);
        }
        return;
    }
    bid -= 1536;
    const float* in;
    unsigned short* outp;
    int R, Cc, gx;
    if (bid < 192) { in = W_xproj; outp = WxT; R = 2048; Cc = 96; gx = 3; }
    else { bid -= 192; in = W_dt; outp = WdtT; R = 64; Cc = 2048; gx = 64; }
    const int bx = bid % gx, by = bid / gx;
    __shared__ float t[32][33];
    const int tx = threadIdx.x & 31, ty = threadIdx.x >> 5;
    const int c0 = bx * 32, r0 = by * 32;
    for (int i = ty; i < 32; i += 8)
        t[i][tx] = in[(size_t)(r0 + i) * Cc + c0 + tx];
    __syncthreads();
    for (int i = ty; i < 32; i += 8)
        outp[(size_t)(c0 + i) * R + r0 + tx] = f2bf(t[tx][i]);
}

// ===== 256x128 8-wave 2-phase MFMA GEMM (xz) — r13-proven =====
template <int EPI, typename CT>
__global__ __launch_bounds__(512, 4) void gemm_bm256(
    const unsigned short* __restrict__ A, const unsigned short* __restrict__ Bt,
    CT* __restrict__ C, CT* __restrict__ C2, int M, int N, int K) {
    __shared__ __align__(16) unsigned short As[2][8192];
    __shared__ __align__(16) unsigned short Bs[2][4096];
    const int tid = threadIdx.x;
    const int lane = tid & 63;
    const int w8 = tid >> 6;
    const int wm = w8 >> 1, wn = w8 & 1;
    const int nwg = gridDim.x * gridDim.y;
    const int wg = xcd_swz(blockIdx.y * gridDim.x + blockIdx.x, nwg);
    const int m0 = (wg / gridDim.x) * 256, n0 = (wg % gridDim.x) * 128;
    const int fr = lane & 15, kg = lane >> 4;
    const int kswz = ((kg ^ ((fr >> 1) & 3)) << 3);
    const int r0 = tid >> 2;
    const int d0 = tid * 8;
    const int cs8 = (((tid & 3) ^ ((tid >> 3) & 3)) << 3);
    const int nt = K / 32;

    f32x4 acc[4][4];
#pragma unroll
    for (int m = 0; m < 4; m++)
#pragma unroll
        for (int n = 0; n < 4; n++) acc[m][n] = (f32x4){0.f, 0.f, 0.f, 0.f};

#define STAGE(buf, k0)                                                           \
    {                                                                            \
        gld_lds16(&A[(size_t)(m0 + r0) * K + (k0) + cs8], &As[buf][d0]);         \
        gld_lds16(&A[(size_t)(m0 + 128 + r0) * K + (k0) + cs8],                  \
                  &As[buf][d0 + 4096]);                                          \
        gld_lds16(&Bt[(size_t)(n0 + r0) * K + (k0) + cs8], &Bs[buf][d0]);        \
    }

    STAGE(0, 0);
    __syncthreads();

    int cur = 0;
    for (int t = 0; t < nt; t++) {
        if (t + 1 < nt) STAGE(cur ^ 1, (t + 1) * 32);
        short8 a[4], b[4];
#pragma unroll
        for (int m = 0; m < 4; m++)
            a[m] = *reinterpret_cast<const short8*>(
                &As[cur][(wm * 64 + m * 16 + fr) * 32 + kswz]);
#pragma unroll
        for (int n = 0; n < 4; n++)
            b[n] = *reinterpret_cast<const short8*>(
                &Bs[cur][(wn * 64 + n * 16 + fr) * 32 + kswz]);
#pragma unroll
        for (int m = 0; m < 4; m++)
#pragma unroll
            for (int n = 0; n < 4; n++)
                acc[m][n] = __builtin_amdgcn_mfma_f32_16x16x32_bf16(
                    a[m], b[n], acc[m][n], 0, 0, 0);
        __syncthreads();
        cur ^= 1;
    }
#undef STAGE

    const int g4 = kg * 4;
#pragma unroll
    for (int m = 0; m < 4; m++)
#pragma unroll
        for (int n = 0; n < 4; n++)
#pragma unroll
            for (int j = 0; j < 4; j++) {
                int mm = m0 + wm * 64 + m * 16 + g4 + j;
                int nn = n0 + wn * 64 + n * 16 + fr;
                float v = acc[m][n][j];
                if (EPI == 1) {
                    if (nn < DINNER)
                        C[(size_t)mm * DINNER + nn] = f2bf(v);
                    else
                        C2[(size_t)mm * DINNER + (nn - DINNER)] = f2bf(silu_f(v));
                } else {
                    if constexpr (sizeof(CT) == 2)
                        C[(size_t)mm * N + nn] = f2bf(v);
                    else
                        C[(size_t)mm * N + nn] = v;
                }
            }
}

// ---- 128xBN 2-phase MFMA GEMM (out; BN=64 -> 512 blocks) ----
template <int BN, typename CT>
__global__ __launch_bounds__(256) void gemm_mfma(
    const unsigned short* __restrict__ A, const unsigned short* __restrict__ Bt,
    CT* __restrict__ C, int M, int N, int K) {
    constexpr int NF = BN / 32;
    __shared__ __align__(16) unsigned short As[2][4096];
    __shared__ __align__(16) unsigned short Bs[2][BN * 32];
    const int tid = threadIdx.x;
    const int lane = tid & 63;
    const int wid = tid >> 6;
    const int wr = wid >> 1, wc = wid & 1;
    const int nwg = gridDim.x * gridDim.y;
    const int wg = xcd_swz(blockIdx.y * gridDim.x + blockIdx.x, nwg);
    const int m0 = (wg / gridDim.x) * 128, n0 = (wg % gridDim.x) * BN;

    const int r0 = tid >> 2;
    const int r1 = r0 + 64;
    const int d0 = tid * 8;
    const int d1 = d0 + 2048;
    const int cs8 = (((tid & 3) ^ ((tid >> 3) & 3)) << 3);

    f32x4 acc[4][NF];
#pragma unroll
    for (int m = 0; m < 4; m++)
#pragma unroll
        for (int n = 0; n < NF; n++) acc[m][n] = (f32x4){0.f, 0.f, 0.f, 0.f};

    const int fr = lane & 15;
    const int kg = lane >> 4;
    const int kswz = ((kg ^ ((fr >> 1) & 3)) << 3);
    const int nt = K / 32;

    gld_lds16(&A[(size_t)(m0 + r0) * K + cs8], &As[0][d0]);
    gld_lds16(&A[(size_t)(m0 + r1) * K + cs8], &As[0][d1]);
    gld_lds16(&Bt[(size_t)(n0 + r0) * K + cs8], &Bs[0][d0]);
    if constexpr (BN == 128)
        gld_lds16(&Bt[(size_t)(n0 + r1) * K + cs8], &Bs[0][d1]);
    __syncthreads();

    int cur = 0;
    for (int t = 0; t < nt; t++) {
        if (t + 1 < nt) {
            const int k0 = (t + 1) * 32;
            gld_lds16(&A[(size_t)(m0 + r0) * K + k0 + cs8], &As[cur ^ 1][d0]);
            gld_lds16(&A[(size_t)(m0 + r1) * K + k0 + cs8], &As[cur ^ 1][d1]);
            gld_lds16(&Bt[(size_t)(n0 + r0) * K + k0 + cs8], &Bs[cur ^ 1][d0]);
            if constexpr (BN == 128)
                gld_lds16(&Bt[(size_t)(n0 + r1) * K + k0 + cs8], &Bs[cur ^ 1][d1]);
        }
        short8 a[4], b[NF];
#pragma unroll
        for (int m = 0; m < 4; m++)
            a[m] = *reinterpret_cast<const short8*>(
                &As[cur][(wr * 64 + m * 16 + fr) * 32 + kswz]);
#pragma unroll
        for (int n = 0; n < NF; n++)
            b[n] = *reinterpret_cast<const short8*>(
                &Bs[cur][(wc * (BN / 2) + n * 16 + fr) * 32 + kswz]);
#pragma unroll
        for (int m = 0; m < 4; m++)
#pragma unroll
            for (int n = 0; n < NF; n++)
                acc[m][n] = __builtin_amdgcn_mfma_f32_16x16x32_bf16(
                    a[m], b[n], acc[m][n], 0, 0, 0);
        __syncthreads();
        cur ^= 1;
    }

    const int g4 = (lane >> 4) * 4;
#pragma unroll
    for (int m = 0; m < 4; m++)
#pragma unroll
        for (int n = 0; n < NF; n++)
#pragma unroll
            for (int j = 0; j < 4; j++) {
                int mm = m0 + wr * 64 + m * 16 + g4 + j;
                int nn = n0 + wc * (BN / 2) + n * 16 + fr;
                float v = acc[m][n][j];
                if constexpr (sizeof(CT) == 2)
                    C[(size_t)mm * N + nn] = f2bf(v);
                else
                    C[(size_t)mm * N + nn] = v;
            }
}

// ---- dt: LDS-free direct MFMA, K=64 ----
__global__ __launch_bounds__(256) void dt_gemm(
    const unsigned short* __restrict__ dtin,  // [M][64]
    const unsigned short* __restrict__ WdtT,  // [DINNER][64]
    const float* __restrict__ bias,
    unsigned short* __restrict__ dtout) {     // [M][DINNER]
    const int lane = threadIdx.x & 63;
    const int wid = threadIdx.x >> 6;
    const int mt = wid >> 1, nh = wid & 1;
    const int m0 = blockIdx.x * 32;
    const int n0 = blockIdx.y * 128 + nh * 64;
    const int fr = lane & 15, kg = lane >> 4;

    f32x4 acc[4];
#pragma unroll
    for (int i = 0; i < 4; i++) acc[i] = (f32x4){0.f, 0.f, 0.f, 0.f};

#pragma unroll
    for (int step = 0; step < 2; step++) {
        short8 a = *reinterpret_cast<const short8*>(
            &dtin[(size_t)(m0 + mt * 16 + fr) * DTRANK + step * 32 + kg * 8]);
#pragma unroll
        for (int nt = 0; nt < 4; nt++) {
            short8 b = *reinterpret_cast<const short8*>(
                &WdtT[(size_t)(n0 + nt * 16 + fr) * DTRANK + step * 32 + kg * 8]);
            acc[nt] = __builtin_amdgcn_mfma_f32_16x16x32_bf16(a, b, acc[nt], 0, 0, 0);
        }
    }
    const int g4 = kg * 4;
#pragma unroll
    for (int nt = 0; nt < 4; nt++)
#pragma unroll
        for (int j = 0; j < 4; j++) {
            int m = m0 + mt * 16 + g4 + j;
            int n = n0 + nt * 16 + fr;
            dtout[(size_t)m * DINNER + n] = f2bf(softplus_f(acc[nt][j] + bias[n]));
        }
}

// ---- FUSED conv+proj (r15-proven) ----
__global__ __launch_bounds__(256) void proj_conv(
    const unsigned short* __restrict__ xbpre, const float* __restrict__ w,
    const float* __restrict__ bconv, const unsigned short* __restrict__ WxT,
    unsigned short* __restrict__ xb_out, float* __restrict__ pp) {
    __shared__ __align__(16) unsigned short xbs[32][520];
    const int mb = blockIdx.x, kc = blockIdx.y;
    const int m0 = mb * 32;
    const int D0 = kc * KCH;

    {
        const int tcol = threadIdx.x & 63;
        const int trow = threadIdx.x >> 6;
        const int dd = D0 + tcol * 8;
        float wk0[8], wk1[8], wk2[8], wk3[8], bb[8];
#pragma unroll
        for (int q = 0; q < 8; q++) {
            float4 wv = *reinterpret_cast<const float4*>(&w[(dd + q) * 4]);
            wk0[q] = wv.x; wk1[q] = wv.y; wk2[q] = wv.z; wk3[q] = wv.w;
        }
        {
            float4 b0 = *reinterpret_cast<const float4*>(&bconv[dd]);
            float4 b1 = *reinterpret_cast<const float4*>(&bconv[dd + 4]);
            bb[0] = b0.x; bb[1] = b0.y; bb[2] = b0.z; bb[3] = b0.w;
            bb[4] = b1.x; bb[5] = b1.y; bb[6] = b1.z; bb[7] = b1.w;
        }
        const int rbase = m0 + trow * 8;
        const int tloc0 = rbase & (LSEQ - 1);
        float xm3[8], xm2[8], xm1[8];
        if (tloc0 >= 3) {
            short8 v3 = *reinterpret_cast<const short8*>(&xbpre[(size_t)(rbase - 3) * DINNER + dd]);
            short8 v2 = *reinterpret_cast<const short8*>(&xbpre[(size_t)(rbase - 2) * DINNER + dd]);
            short8 v1 = *reinterpret_cast<const short8*>(&xbpre[(size_t)(rbase - 1) * DINNER + dd]);
#pragma unroll
            for (int q = 0; q < 8; q++) {
                xm3[q] = bf2f((unsigned short)v3[q]);
                xm2[q] = bf2f((unsigned short)v2[q]);
                xm1[q] = bf2f((unsigned short)v1[q]);
            }
        } else {
#pragma unroll
            for (int q = 0; q < 8; q++) { xm3[q] = 0.f; xm2[q] = 0.f; xm1[q] = 0.f; }
        }
#pragma unroll
        for (int rr = 0; rr < 8; rr++) {
            short8 vc = *reinterpret_cast<const short8*>(
                &xbpre[(size_t)(rbase + rr) * DINNER + dd]);
            float xc[8];
            short8 o;
#pragma unroll
            for (int q = 0; q < 8; q++) {
                xc[q] = bf2f((unsigned short)vc[q]);
                float a = bb[q];
                a = fmaf(wk0[q], xm3[q], a);
                a = fmaf(wk1[q], xm2[q], a);
                a = fmaf(wk2[q], xm1[q], a);
                a = fmaf(wk3[q], xc[q], a);
                o[q] = (short)f2bf(silu_f(a));
            }
            *reinterpret_cast<short8*>(&xbs[trow * 8 + rr][tcol * 8]) = o;
            *reinterpret_cast<short8*>(
                &xb_out[(size_t)(rbase + rr) * DINNER + dd]) = o;
#pragma unroll
            for (int q = 0; q < 8; q++) { xm3[q] = xm2[q]; xm2[q] = xm1[q]; xm1[q] = xc[q]; }
        }
    }
    __syncthreads();

    const int lane = threadIdx.x & 63;
    const int wid = threadIdx.x >> 6;
    const int mt = wid >> 1;
    const int nh = wid & 1;
    const int fr = lane & 15;
    const int kg = lane >> 4;

    f32x4 acc[3];
#pragma unroll
    for (int i = 0; i < 3; i++) acc[i] = (f32x4){0.f, 0.f, 0.f, 0.f};

    for (int step = 0; step < KCH / 32; step++) {
        short8 a = *reinterpret_cast<const short8*>(
            &xbs[mt * 16 + fr][step * 32 + kg * 8]);
#pragma unroll
        for (int nt = 0; nt < 3; nt++) {
            int nrow = nh * 48 + nt * 16 + fr;
            short8 b = *reinterpret_cast<const short8*>(
                &WxT[(size_t)nrow * DINNER + D0 + step * 32 + kg * 8]);
            acc[nt] = __builtin_amdgcn_mfma_f32_16x16x32_bf16(a, b, acc[nt], 0, 0, 0);
        }
    }
    const int g4 = kg * 4;
#pragma unroll
    for (int nt = 0; nt < 3; nt++)
#pragma unroll
        for (int j = 0; j < 4; j++) {
            int m = m0 + mt * 16 + g4 + j;
            int n = nh * 48 + nt * 16 + fr;
            pp[((size_t)kc * (BSZ * LSEQ) + m) * NPROJ + n] = acc[nt][j];
        }
}

// reduce split-K partials; emit fp32 proj + bf16 dt_in (cols < DTRANK)
__global__ __launch_bounds__(256) void proj_reduce(
    const float* __restrict__ pp, float* __restrict__ proj,
    unsigned short* __restrict__ dtin) {
    int i = blockIdx.x * 256 + threadIdx.x;
    if (i >= BSZ * LSEQ * NPROJ) return;
    float s = 0.f;
#pragma unroll
    for (int kc = 0; kc < KS; kc++)
        s += pp[(size_t)kc * BSZ * LSEQ * NPROJ + i];
    proj[i] = s;
    int m = i / NPROJ;
    int n = i - m * NPROJ;
    if (n < DTRANK) dtin[(size_t)m * DTRANK + n] = f2bf(s);
}

// ---- FUSED 3-phase selective scan (cooperative, grid-wide sync) ----
// 512 blocks x 256 thr; block = (bc = blockIdx>>3) x 256-d slice.
// Phase 1: scan from h=0, cache (dt,xb) pairs as packed u32 in LDS,
//          write aprod/hend. grid.sync.
// Phase 2: first 65536 threads do the serial chunk combine (hstart in-place
//          over aprod). grid.sync.
// Phase 3: rescan from hstart, dt/xb from LDS, write ybf.
// LDS: dx 64KB + B 4KB + C 4KB = 72KB -> exactly 2 blocks/CU x 256 CU = 512.
__global__ __launch_bounds__(256) void scan_fused(
    const unsigned short* __restrict__ xb, const unsigned short* __restrict__ dt,
    const float* __restrict__ proj, const float* __restrict__ A_log,
    const float* __restrict__ Dp, const unsigned short* __restrict__ sz,
    float* __restrict__ aprod, float* __restrict__ hend,
    unsigned short* __restrict__ ybf) {
    extern __shared__ __align__(16) char smem[];
    unsigned int* dxs = (unsigned int*)smem;          // [LC][256]
    float* Bsh = (float*)(smem + LC * 256 * 4);       // [LC][16]
    float* Csh = Bsh + LC * DSTATE;                   // [LC][16]

    cg::grid_group grid = cg::this_grid();

    const int tid = threadIdx.x;
    const int bc = blockIdx.x >> 3;            // b*NC + c
    const int c = bc & (NC - 1);
    const int b = bc >> 5;
    const int d = ((blockIdx.x & 7) << 8) + tid;

    // load B and C rows for this chunk
    for (int idx = tid; idx < LC * 2 * DSTATE; idx += 256) {
        int ti = idx >> 5, j = idx & 31;
        float v = proj[(size_t)(b * LSEQ + c * LC + ti) * NPROJ + DTRANK + j];
        if (j < DSTATE) Bsh[ti * DSTATE + j] = v;
        else            Csh[ti * DSTATE + (j - DSTATE)] = v;
    }
    __syncthreads();

    float Av[DSTATE], h[DSTATE], ap[DSTATE];
#pragma unroll
    for (int s = 0; s < DSTATE; s++) {
        Av[s] = -expf(A_log[d * DSTATE + s]);
        h[s] = 0.f;
        ap[s] = 1.f;
    }

    // ---- phase 1 ----
    for (int i = 0; i < LC; i++) {
        size_t base = (size_t)(b * LSEQ + c * LC + i) * DINNER + d;
        unsigned short dtb = dt[base];
        unsigned short xbb = xb[base];
        dxs[i * 256 + tid] = ((unsigned)dtb << 16) | (unsigned)xbb;
        float dtv = bf2f(dtb);
        float xv = bf2f(xbb);
        float dx = dtv * xv;
#pragma unroll
        for (int s = 0; s < DSTATE; s++) {
            float dA = __expf(dtv * Av[s]);
            ap[s] *= dA;
            h[s] = fmaf(dA, h[s], dx * Bsh[i * DSTATE + s]);
        }
    }
    size_t o = ((size_t)bc * DINNER + d) * DSTATE;
#pragma unroll
    for (int q = 0; q < 4; q++) {
        *reinterpret_cast<float4*>(&aprod[o + q * 4]) =
            make_float4(ap[4 * q], ap[4 * q + 1], ap[4 * q + 2], ap[4 * q + 3]);
        *reinterpret_cast<float4*>(&hend[o + q * 4]) =
            make_float4(h[4 * q], h[4 * q + 1], h[4 * q + 2], h[4 * q + 3]);
    }
    __threadfence();
    grid.sync();

    // ---- phase 2: serial combine (first 65536 threads) ----
    {
        const int tg2 = blockIdx.x * 256 + tid;
        if (tg2 < BSZ * DINNER * DSTATE) {
            const int s2 = tg2 & (DSTATE - 1);
            const int d2 = (tg2 >> 4) & (DINNER - 1);
            const int b2 = tg2 >> 15;
            float hh = 0.f;
            for (int c2 = 0; c2 < NC; c2++) {
                size_t o2 = ((size_t)((b2 * NC + c2) * DINNER) + d2) * DSTATE + s2;
                float a = aprod[o2];
                float e = hend[o2];
                aprod[o2] = hh;
                hh = fmaf(a, hh, e);
            }
        }
    }
    __threadfence();
    grid.sync();

    // ---- phase 3: rescan from hstart, operands from LDS ----
#pragma unroll
    for (int q = 0; q < 4; q++) {
        float4 hv = *reinterpret_cast<const float4*>(&aprod[o + q * 4]);
        h[4 * q] = hv.x; h[4 * q + 1] = hv.y; h[4 * q + 2] = hv.z; h[4 * q + 3] = hv.w;
    }
    const float Dd = Dp[d];
    for (int i = 0; i < LC; i++) {
        size_t base = (size_t)(b * LSEQ + c * LC + i) * DINNER + d;
        unsigned v = dxs[i * 256 + tid];
        float dtv = bf2f((unsigned short)(v >> 16));
        float xv = bf2f((unsigned short)(v & 0xffffu));
        float szv = bf2f(sz[base]);
        float dx = dtv * xv;
        float p = 0.f;
#pragma unroll
        for (int s = 0; s < DSTATE; s++) {
            float dA = __expf(dtv * Av[s]);
            h[s] = fmaf(dA, h[s], dx * Bsh[i * DSTATE + s]);
            p = fmaf(h[s], Csh[i * DSTATE + s], p);
        }
        ybf[base] = f2bf((p + Dd * xv) * szv);
    }
}

extern "C" void kernel_launch(void* const* d_in, const int* in_sizes, int n_in,
                              void* d_out, int out_size, void* d_ws,
                              size_t ws_size, hipStream_t stream) {
    const float* x = (const float*)d_in[0];
    const float* W_in = (const float*)d_in[1];
    const float* conv_w = (const float*)d_in[2];
    const float* conv_b = (const float*)d_in[3];
    const float* W_xproj = (const float*)d_in[4];
    const float* W_dt = (const float*)d_in[5];
    const float* b_dt = (const float*)d_in[6];
    const float* A_log = (const float*)d_in[7];
    const float* Dp = (const float*)d_in[8];
    const float* W_out = (const float*)d_in[9];
    float* out = (float*)d_out;

    char* ws = (char*)d_ws;
    const size_t MB = 1u << 20;
    float* pp    = (float*)(ws);
    float* aprod = (float*)(ws);
    float* hend  = (float*)(ws + 8 * MB);
    unsigned short* xbpre_bf = (unsigned short*)(ws + 16 * MB);  // 16 MB
    unsigned short* ybf      = (unsigned short*)(ws + 16 * MB);  // 16 MB (after proj_conv)
    unsigned short* sz_bf    = (unsigned short*)(ws + 32 * MB);  // 16 MB
    unsigned short* xb_bf    = (unsigned short*)(ws + 48 * MB);  // 16 MB
    unsigned short* dt_bf    = (unsigned short*)(ws + 64 * MB);  // 16 MB
    float* projbuf           = (float*)(ws + 88 * MB);           // 1.5 MB
    unsigned short* dtin_bf  = (unsigned short*)(ws + 90 * MB);  // 0.5 MB
    unsigned short* xbf      = (unsigned short*)(ws + 91 * MB);  // 8 MB
    unsigned short* WinT     = (unsigned short*)(ws + 99 * MB);  // 8 MB
    unsigned short* WoutT    = (unsigned short*)(ws + 107 * MB); // 4 MB
    unsigned short* WxT      = (unsigned short*)(ws + 111 * MB); // 384 KB
    unsigned short* WdtT     = (unsigned short*)(ws + 112 * MB); // 256 KB

    const int M = BSZ * LSEQ; // 4096
    dim3 blk(256);

    // 0. fused prep
    prep_kernel<<<dim3(4096 + 1024 + 512 + 192 + 128), blk, 0, stream>>>(
        x, W_in, W_out, W_xproj, W_dt, xbf, WinT, WoutT, WxT, WdtT);

    // 1. xz = x @ W_in — 256x128 tile, 512 blocks
    gemm_bm256<1, unsigned short><<<dim3((2 * DINNER) / 128, M / 256), dim3(512),
                                    0, stream>>>(
        xbf, WinT, xbpre_bf, sz_bf, M, 2 * DINNER, DMODEL);

    // 2+3. fused conv + proj split-K
    proj_conv<<<dim3(M / 32, KS), blk, 0, stream>>>(
        xbpre_bf, conv_w, conv_b, WxT, xb_bf, pp);
    proj_reduce<<<dim3((M * NPROJ) / 256), blk, 0, stream>>>(pp, projbuf, dtin_bf);

    // 4. dt = softplus(dt_in @ W_dt + b_dt)
    dt_gemm<<<dim3(M / 32, DINNER / 128), blk, 0, stream>>>(
        dtin_bf, WdtT, b_dt, dt_bf);

    // 5. fused 3-phase scan (cooperative; 72 KB dyn LDS, 512 blocks)
    {
        void* kargs[] = {(void*)&xb_bf, (void*)&dt_bf, (void*)&projbuf,
                         (void*)&A_log, (void*)&Dp, (void*)&sz_bf,
                         (void*)&aprod, (void*)&hend, (void*)&ybf};
        hipLaunchCooperativeKernel((const void*)scan_fused, dim3(512), dim3(256),
                                   kargs, LC * 256 * 4 + 2 * LC * DSTATE * 4,
                                   stream);
    }

    // 6. out = y @ W_out (2-phase 128x64)
    gemm_mfma<64, float><<<dim3(DMODEL / 64, M / 128), blk, 0, stream>>>(
        ybf, WoutT, out, M, DMODEL, DINNER);
}

// Round 17
// 249.173 us; speedup vs baseline: 2.0647x; 2.0647x over previous
//
#include <hip/hip_runtime.h>
#include <hip/hip_bf16.h>
#include <math.h>

#define BSZ 2
#define LSEQ 2048
#define DMODEL 1024
#define DSTATE 16
#define DCONV 4
#define DINNER 2048
#define DTRANK 64
#define NPROJ (DTRANK + 2 * DSTATE) // 96
#define NC 32   // scan chunks
#define LC 64   // steps per chunk
#define KS 4    // proj split-K chunks
#define KCH (DINNER / KS) // 512

using short8 = __attribute__((ext_vector_type(8))) short;
using f32x4 = __attribute__((ext_vector_type(4))) float;
using u16x4 = __attribute__((ext_vector_type(4))) unsigned short;

__device__ __forceinline__ float silu_f(float v) {
    return v / (1.f + expf(-v));
}
__device__ __forceinline__ float softplus_f(float v) {
    return fmaxf(v, 0.f) + log1pf(expf(-fabsf(v)));
}
// fp32 -> bf16 bits, round-to-nearest-even
__device__ __forceinline__ unsigned short f2bf(float f) {
    unsigned u = __builtin_bit_cast(unsigned, f);
    u += 0x7fffu + ((u >> 16) & 1u);
    return (unsigned short)(u >> 16);
}
__device__ __forceinline__ float bf2f(unsigned short u) {
    unsigned x = ((unsigned)u) << 16;
    return __builtin_bit_cast(float, x);
}

__device__ __forceinline__ void gld_lds16(const unsigned short* g, unsigned short* l) {
    __builtin_amdgcn_global_load_lds(
        (const __attribute__((address_space(1))) unsigned int*)g,
        (__attribute__((address_space(3))) unsigned int*)l, 16, 0, 0);
}

// bijective XCD swizzle (requires nwg % 8 == 0)
__device__ __forceinline__ int xcd_swz(int wg, int nwg) {
    return (wg & 7) * (nwg >> 3) + (wg >> 3);
}

// ---- fused prep: x->bf16 + weight transposes ----
__global__ __launch_bounds__(256) void prep_kernel(
    const float* __restrict__ x, const float* __restrict__ W_in,
    const float* __restrict__ W_out, const float* __restrict__ W_xproj,
    const float* __restrict__ W_dt,
    unsigned short* __restrict__ xbf, unsigned short* __restrict__ WinT,
    unsigned short* __restrict__ WoutT, unsigned short* __restrict__ WxT,
    unsigned short* __restrict__ WdtT) {
    int bid = blockIdx.x;
    if (bid < 4096) { // x -> bf16
        int i = bid * 256 + threadIdx.x;
        float4 v = reinterpret_cast<const float4*>(x)[i];
        u16x4 o = {f2bf(v.x), f2bf(v.y), f2bf(v.z), f2bf(v.w)};
        reinterpret_cast<u16x4*>(xbf)[i] = o;
        return;
    }
    bid -= 4096;
    if (bid < 1024 + 512) { // 64x64 transposes: W_in, W_out
        const float* in;
        unsigned short* outp;
        int R, Cc, gx;
        if (bid < 1024) { in = W_in; outp = WinT; R = 1024; Cc = 4096; gx = 64; }
        else { bid -= 1024; in = W_out; outp = WoutT; R = 2048; Cc = 1024; gx = 16; }
        const int bx = bid % gx, by = bid / gx;
        __shared__ float t64[64][65];
        const int tx = threadIdx.x & 63, ty = threadIdx.x >> 6; // 64 x 4
        const int c0 = bx * 64, r0 = by * 64;
#pragma unroll
        for (int i = 0; i < 16; i++)
            t64[ty + 4 * i][tx] = in[(size_t)(r0 + ty + 4 * i) * Cc + c0 + tx];
        __syncthreads();
#pragma unroll
        for (int i = 0; i < 16; i++) {
            int rr = ty + 4 * i;
            outp[(size_t)(c0 + rr) * R + r0 + tx] = f2bf(t64[tx][rr]);
        }
        return;
    }
    bid -= 1536;
    const float* in;
    unsigned short* outp;
    int R, Cc, gx;
    if (bid < 192) { in = W_xproj; outp = WxT; R = 2048; Cc = 96; gx = 3; }
    else { bid -= 192; in = W_dt; outp = WdtT; R = 64; Cc = 2048; gx = 64; }
    const int bx = bid % gx, by = bid / gx;
    __shared__ float t[32][33];
    const int tx = threadIdx.x & 31, ty = threadIdx.x >> 5;
    const int c0 = bx * 32, r0 = by * 32;
    for (int i = ty; i < 32; i += 8)
        t[i][tx] = in[(size_t)(r0 + i) * Cc + c0 + tx];
    __syncthreads();
    for (int i = ty; i < 32; i += 8)
        outp[(size_t)(c0 + i) * R + r0 + tx] = f2bf(t[tx][i]);
}

// ===== 256x128 8-wave 2-phase MFMA GEMM (xz) — r13-proven =====
template <int EPI, typename CT>
__global__ __launch_bounds__(512, 4) void gemm_bm256(
    const unsigned short* __restrict__ A, const unsigned short* __restrict__ Bt,
    CT* __restrict__ C, CT* __restrict__ C2, int M, int N, int K) {
    __shared__ __align__(16) unsigned short As[2][8192];
    __shared__ __align__(16) unsigned short Bs[2][4096];
    const int tid = threadIdx.x;
    const int lane = tid & 63;
    const int w8 = tid >> 6;
    const int wm = w8 >> 1, wn = w8 & 1;
    const int nwg = gridDim.x * gridDim.y;
    const int wg = xcd_swz(blockIdx.y * gridDim.x + blockIdx.x, nwg);
    const int m0 = (wg / gridDim.x) * 256, n0 = (wg % gridDim.x) * 128;
    const int fr = lane & 15, kg = lane >> 4;
    const int kswz = ((kg ^ ((fr >> 1) & 3)) << 3);
    const int r0 = tid >> 2;
    const int d0 = tid * 8;
    const int cs8 = (((tid & 3) ^ ((tid >> 3) & 3)) << 3);
    const int nt = K / 32;

    f32x4 acc[4][4];
#pragma unroll
    for (int m = 0; m < 4; m++)
#pragma unroll
        for (int n = 0; n < 4; n++) acc[m][n] = (f32x4){0.f, 0.f, 0.f, 0.f};

#define STAGE(buf, k0)                                                           \
    {                                                                            \
        gld_lds16(&A[(size_t)(m0 + r0) * K + (k0) + cs8], &As[buf][d0]);         \
        gld_lds16(&A[(size_t)(m0 + 128 + r0) * K + (k0) + cs8],                  \
                  &As[buf][d0 + 4096]);                                          \
        gld_lds16(&Bt[(size_t)(n0 + r0) * K + (k0) + cs8], &Bs[buf][d0]);        \
    }

    STAGE(0, 0);
    __syncthreads();

    int cur = 0;
    for (int t = 0; t < nt; t++) {
        if (t + 1 < nt) STAGE(cur ^ 1, (t + 1) * 32);
        short8 a[4], b[4];
#pragma unroll
        for (int m = 0; m < 4; m++)
            a[m] = *reinterpret_cast<const short8*>(
                &As[cur][(wm * 64 + m * 16 + fr) * 32 + kswz]);
#pragma unroll
        for (int n = 0; n < 4; n++)
            b[n] = *reinterpret_cast<const short8*>(
                &Bs[cur][(wn * 64 + n * 16 + fr) * 32 + kswz]);
#pragma unroll
        for (int m = 0; m < 4; m++)
#pragma unroll
            for (int n = 0; n < 4; n++)
                acc[m][n] = __builtin_amdgcn_mfma_f32_16x16x32_bf16(
                    a[m], b[n], acc[m][n], 0, 0, 0);
        __syncthreads();
        cur ^= 1;
    }
#undef STAGE

    const int g4 = kg * 4;
#pragma unroll
    for (int m = 0; m < 4; m++)
#pragma unroll
        for (int n = 0; n < 4; n++)
#pragma unroll
            for (int j = 0; j < 4; j++) {
                int mm = m0 + wm * 64 + m * 16 + g4 + j;
                int nn = n0 + wn * 64 + n * 16 + fr;
                float v = acc[m][n][j];
                if (EPI == 1) {
                    if (nn < DINNER)
                        C[(size_t)mm * DINNER + nn] = f2bf(v);
                    else
                        C2[(size_t)mm * DINNER + (nn - DINNER)] = f2bf(silu_f(v));
                } else {
                    if constexpr (sizeof(CT) == 2)
                        C[(size_t)mm * N + nn] = f2bf(v);
                    else
                        C[(size_t)mm * N + nn] = v;
                }
            }
}

// ---- 128xBN 2-phase MFMA GEMM (out; BN=64 -> 512 blocks) ----
template <int BN, typename CT>
__global__ __launch_bounds__(256) void gemm_mfma(
    const unsigned short* __restrict__ A, const unsigned short* __restrict__ Bt,
    CT* __restrict__ C, int M, int N, int K) {
    constexpr int NF = BN / 32;
    __shared__ __align__(16) unsigned short As[2][4096];
    __shared__ __align__(16) unsigned short Bs[2][BN * 32];
    const int tid = threadIdx.x;
    const int lane = tid & 63;
    const int wid = tid >> 6;
    const int wr = wid >> 1, wc = wid & 1;
    const int nwg = gridDim.x * gridDim.y;
    const int wg = xcd_swz(blockIdx.y * gridDim.x + blockIdx.x, nwg);
    const int m0 = (wg / gridDim.x) * 128, n0 = (wg % gridDim.x) * BN;

    const int r0 = tid >> 2;
    const int r1 = r0 + 64;
    const int d0 = tid * 8;
    const int d1 = d0 + 2048;
    const int cs8 = (((tid & 3) ^ ((tid >> 3) & 3)) << 3);

    f32x4 acc[4][NF];
#pragma unroll
    for (int m = 0; m < 4; m++)
#pragma unroll
        for (int n = 0; n < NF; n++) acc[m][n] = (f32x4){0.f, 0.f, 0.f, 0.f};

    const int fr = lane & 15;
    const int kg = lane >> 4;
    const int kswz = ((kg ^ ((fr >> 1) & 3)) << 3);
    const int nt = K / 32;

    gld_lds16(&A[(size_t)(m0 + r0) * K + cs8], &As[0][d0]);
    gld_lds16(&A[(size_t)(m0 + r1) * K + cs8], &As[0][d1]);
    gld_lds16(&Bt[(size_t)(n0 + r0) * K + cs8], &Bs[0][d0]);
    if constexpr (BN == 128)
        gld_lds16(&Bt[(size_t)(n0 + r1) * K + cs8], &Bs[0][d1]);
    __syncthreads();

    int cur = 0;
    for (int t = 0; t < nt; t++) {
        if (t + 1 < nt) {
            const int k0 = (t + 1) * 32;
            gld_lds16(&A[(size_t)(m0 + r0) * K + k0 + cs8], &As[cur ^ 1][d0]);
            gld_lds16(&A[(size_t)(m0 + r1) * K + k0 + cs8], &As[cur ^ 1][d1]);
            gld_lds16(&Bt[(size_t)(n0 + r0) * K + k0 + cs8], &Bs[cur ^ 1][d0]);
            if constexpr (BN == 128)
                gld_lds16(&Bt[(size_t)(n0 + r1) * K + k0 + cs8], &Bs[cur ^ 1][d1]);
        }
        short8 a[4], b[NF];
#pragma unroll
        for (int m = 0; m < 4; m++)
            a[m] = *reinterpret_cast<const short8*>(
                &As[cur][(wr * 64 + m * 16 + fr) * 32 + kswz]);
#pragma unroll
        for (int n = 0; n < NF; n++)
            b[n] = *reinterpret_cast<const short8*>(
                &Bs[cur][(wc * (BN / 2) + n * 16 + fr) * 32 + kswz]);
#pragma unroll
        for (int m = 0; m < 4; m++)
#pragma unroll
            for (int n = 0; n < NF; n++)
                acc[m][n] = __builtin_amdgcn_mfma_f32_16x16x32_bf16(
                    a[m], b[n], acc[m][n], 0, 0, 0);
        __syncthreads();
        cur ^= 1;
    }

    const int g4 = (lane >> 4) * 4;
#pragma unroll
    for (int m = 0; m < 4; m++)
#pragma unroll
        for (int n = 0; n < NF; n++)
#pragma unroll
            for (int j = 0; j < 4; j++) {
                int mm = m0 + wr * 64 + m * 16 + g4 + j;
                int nn = n0 + wc * (BN / 2) + n * 16 + fr;
                float v = acc[m][n][j];
                if constexpr (sizeof(CT) == 2)
                    C[(size_t)mm * N + nn] = f2bf(v);
                else
                    C[(size_t)mm * N + nn] = v;
            }
}

// ---- dt: LDS-free direct MFMA, K=64 ----
__global__ __launch_bounds__(256) void dt_gemm(
    const unsigned short* __restrict__ dtin,  // [M][64]
    const unsigned short* __restrict__ WdtT,  // [DINNER][64]
    const float* __restrict__ bias,
    unsigned short* __restrict__ dtout) {     // [M][DINNER]
    const int lane = threadIdx.x & 63;
    const int wid = threadIdx.x >> 6;
    const int mt = wid >> 1, nh = wid & 1;
    const int m0 = blockIdx.x * 32;
    const int n0 = blockIdx.y * 128 + nh * 64;
    const int fr = lane & 15, kg = lane >> 4;

    f32x4 acc[4];
#pragma unroll
    for (int i = 0; i < 4; i++) acc[i] = (f32x4){0.f, 0.f, 0.f, 0.f};

#pragma unroll
    for (int step = 0; step < 2; step++) {
        short8 a = *reinterpret_cast<const short8*>(
            &dtin[(size_t)(m0 + mt * 16 + fr) * DTRANK + step * 32 + kg * 8]);
#pragma unroll
        for (int nt = 0; nt < 4; nt++) {
            short8 b = *reinterpret_cast<const short8*>(
                &WdtT[(size_t)(n0 + nt * 16 + fr) * DTRANK + step * 32 + kg * 8]);
            acc[nt] = __builtin_amdgcn_mfma_f32_16x16x32_bf16(a, b, acc[nt], 0, 0, 0);
        }
    }
    const int g4 = kg * 4;
#pragma unroll
    for (int nt = 0; nt < 4; nt++)
#pragma unroll
        for (int j = 0; j < 4; j++) {
            int m = m0 + mt * 16 + g4 + j;
            int n = n0 + nt * 16 + fr;
            dtout[(size_t)m * DINNER + n] = f2bf(softplus_f(acc[nt][j] + bias[n]));
        }
}

// ---- FUSED conv+proj (r15-proven) ----
__global__ __launch_bounds__(256) void proj_conv(
    const unsigned short* __restrict__ xbpre, const float* __restrict__ w,
    const float* __restrict__ bconv, const unsigned short* __restrict__ WxT,
    unsigned short* __restrict__ xb_out, float* __restrict__ pp) {
    __shared__ __align__(16) unsigned short xbs[32][520];
    const int mb = blockIdx.x, kc = blockIdx.y;
    const int m0 = mb * 32;
    const int D0 = kc * KCH;

    {
        const int tcol = threadIdx.x & 63;
        const int trow = threadIdx.x >> 6;
        const int dd = D0 + tcol * 8;
        float wk0[8], wk1[8], wk2[8], wk3[8], bb[8];
#pragma unroll
        for (int q = 0; q < 8; q++) {
            float4 wv = *reinterpret_cast<const float4*>(&w[(dd + q) * 4]);
            wk0[q] = wv.x; wk1[q] = wv.y; wk2[q] = wv.z; wk3[q] = wv.w;
        }
        {
            float4 b0 = *reinterpret_cast<const float4*>(&bconv[dd]);
            float4 b1 = *reinterpret_cast<const float4*>(&bconv[dd + 4]);
            bb[0] = b0.x; bb[1] = b0.y; bb[2] = b0.z; bb[3] = b0.w;
            bb[4] = b1.x; bb[5] = b1.y; bb[6] = b1.z; bb[7] = b1.w;
        }
        const int rbase = m0 + trow * 8;
        const int tloc0 = rbase & (LSEQ - 1);
        float xm3[8], xm2[8], xm1[8];
        if (tloc0 >= 3) {
            short8 v3 = *reinterpret_cast<const short8*>(&xbpre[(size_t)(rbase - 3) * DINNER + dd]);
            short8 v2 = *reinterpret_cast<const short8*>(&xbpre[(size_t)(rbase - 2) * DINNER + dd]);
            short8 v1 = *reinterpret_cast<const short8*>(&xbpre[(size_t)(rbase - 1) * DINNER + dd]);
#pragma unroll
            for (int q = 0; q < 8; q++) {
                xm3[q] = bf2f((unsigned short)v3[q]);
                xm2[q] = bf2f((unsigned short)v2[q]);
                xm1[q] = bf2f((unsigned short)v1[q]);
            }
        } else {
#pragma unroll
            for (int q = 0; q < 8; q++) { xm3[q] = 0.f; xm2[q] = 0.f; xm1[q] = 0.f; }
        }
#pragma unroll
        for (int rr = 0; rr < 8; rr++) {
            short8 vc = *reinterpret_cast<const short8*>(
                &xbpre[(size_t)(rbase + rr) * DINNER + dd]);
            float xc[8];
            short8 o;
#pragma unroll
            for (int q = 0; q < 8; q++) {
                xc[q] = bf2f((unsigned short)vc[q]);
                float a = bb[q];
                a = fmaf(wk0[q], xm3[q], a);
                a = fmaf(wk1[q], xm2[q], a);
                a = fmaf(wk2[q], xm1[q], a);
                a = fmaf(wk3[q], xc[q], a);
                o[q] = (short)f2bf(silu_f(a));
            }
            *reinterpret_cast<short8*>(&xbs[trow * 8 + rr][tcol * 8]) = o;
            *reinterpret_cast<short8*>(
                &xb_out[(size_t)(rbase + rr) * DINNER + dd]) = o;
#pragma unroll
            for (int q = 0; q < 8; q++) { xm3[q] = xm2[q]; xm2[q] = xm1[q]; xm1[q] = xc[q]; }
        }
    }
    __syncthreads();

    const int lane = threadIdx.x & 63;
    const int wid = threadIdx.x >> 6;
    const int mt = wid >> 1;
    const int nh = wid & 1;
    const int fr = lane & 15;
    const int kg = lane >> 4;

    f32x4 acc[3];
#pragma unroll
    for (int i = 0; i < 3; i++) acc[i] = (f32x4){0.f, 0.f, 0.f, 0.f};

    for (int step = 0; step < KCH / 32; step++) {
        short8 a = *reinterpret_cast<const short8*>(
            &xbs[mt * 16 + fr][step * 32 + kg * 8]);
#pragma unroll
        for (int nt = 0; nt < 3; nt++) {
            int nrow = nh * 48 + nt * 16 + fr;
            short8 b = *reinterpret_cast<const short8*>(
                &WxT[(size_t)nrow * DINNER + D0 + step * 32 + kg * 8]);
            acc[nt] = __builtin_amdgcn_mfma_f32_16x16x32_bf16(a, b, acc[nt], 0, 0, 0);
        }
    }
    const int g4 = kg * 4;
#pragma unroll
    for (int nt = 0; nt < 3; nt++)
#pragma unroll
        for (int j = 0; j < 4; j++) {
            int m = m0 + mt * 16 + g4 + j;
            int n = nh * 48 + nt * 16 + fr;
            pp[((size_t)kc * (BSZ * LSEQ) + m) * NPROJ + n] = acc[nt][j];
        }
}

// reduce split-K partials; emit fp32 proj + bf16 dt_in (cols < DTRANK)
__global__ __launch_bounds__(256) void proj_reduce(
    const float* __restrict__ pp, float* __restrict__ proj,
    unsigned short* __restrict__ dtin) {
    int i = blockIdx.x * 256 + threadIdx.x;
    if (i >= BSZ * LSEQ * NPROJ) return;
    float s = 0.f;
#pragma unroll
    for (int kc = 0; kc < KS; kc++)
        s += pp[(size_t)kc * BSZ * LSEQ * NPROJ + i];
    proj[i] = s;
    int m = i / NPROJ;
    int n = i - m * NPROJ;
    if (n < DTRANK) dtin[(size_t)m * DTRANK + n] = f2bf(s);
}

// ---- chunked selective scan (bf16 operands, fp32 state) ----
__global__ __launch_bounds__(256) void scan_pass1(
    const unsigned short* __restrict__ xb, const unsigned short* __restrict__ dt,
    const float* __restrict__ proj, const float* __restrict__ A_log,
    float* __restrict__ aprod, float* __restrict__ hend) {
    __shared__ __align__(16) float Bsh[LC][DSTATE];
    const int tg = blockIdx.x * 256 + threadIdx.x;
    const int d = tg & (DINNER - 1);
    const int bc = tg >> 11;
    const int c = bc & (NC - 1);
    const int b = bc >> 5;

    for (int idx = threadIdx.x; idx < LC * DSTATE; idx += 256) {
        int ti = idx >> 4, j = idx & 15;
        Bsh[ti][j] = proj[(size_t)(b * LSEQ + c * LC + ti) * NPROJ + DTRANK + j];
    }
    __syncthreads();

    float Av[DSTATE], h[DSTATE], ap[DSTATE];
#pragma unroll
    for (int s = 0; s < DSTATE; s++) {
        Av[s] = -expf(A_log[d * DSTATE + s]);
        h[s] = 0.f;
        ap[s] = 1.f;
    }

    for (int i = 0; i < LC; i++) {
        size_t base = (size_t)(b * LSEQ + c * LC + i) * DINNER + d;
        float dtv = bf2f(dt[base]);
        float xv = bf2f(xb[base]);
        float dx = dtv * xv;
        float Bv[DSTATE];
        *reinterpret_cast<float4*>(&Bv[0])  = *reinterpret_cast<const float4*>(&Bsh[i][0]);
        *reinterpret_cast<float4*>(&Bv[4])  = *reinterpret_cast<const float4*>(&Bsh[i][4]);
        *reinterpret_cast<float4*>(&Bv[8])  = *reinterpret_cast<const float4*>(&Bsh[i][8]);
        *reinterpret_cast<float4*>(&Bv[12]) = *reinterpret_cast<const float4*>(&Bsh[i][12]);
#pragma unroll
        for (int s = 0; s < DSTATE; s++) {
            float dA = __expf(dtv * Av[s]);
            ap[s] *= dA;
            h[s] = fmaf(dA, h[s], dx * Bv[s]);
        }
    }

    size_t o = ((size_t)bc * DINNER + d) * DSTATE;
#pragma unroll
    for (int q = 0; q < 4; q++) {
        *reinterpret_cast<float4*>(&aprod[o + q * 4]) =
            make_float4(ap[4 * q], ap[4 * q + 1], ap[4 * q + 2], ap[4 * q + 3]);
        *reinterpret_cast<float4*>(&hend[o + q * 4]) =
            make_float4(h[4 * q], h[4 * q + 1], h[4 * q + 2], h[4 * q + 3]);
    }
}

__global__ __launch_bounds__(256) void scan_pass2(
    float* __restrict__ aprod, const float* __restrict__ hend) {
    const int tg = blockIdx.x * 256 + threadIdx.x;
    const int s = tg & (DSTATE - 1);
    const int d = (tg >> 4) & (DINNER - 1);
    const int b = tg >> 15;
    float h = 0.f;
    for (int c = 0; c < NC; c++) {
        size_t o = ((size_t)((b * NC + c) * DINNER) + d) * DSTATE + s;
        float a = aprod[o];
        float e = hend[o];
        aprod[o] = h;
        h = fmaf(a, h, e);
    }
}

__global__ __launch_bounds__(256) void scan_pass3(
    const unsigned short* __restrict__ xb, const unsigned short* __restrict__ dt,
    const float* __restrict__ proj, const float* __restrict__ hstart,
    const float* __restrict__ A_log, const float* __restrict__ Dp,
    const unsigned short* __restrict__ sz, unsigned short* __restrict__ ybf) {
    __shared__ __align__(16) float Bsh[LC][DSTATE];
    __shared__ __align__(16) float Csh[LC][DSTATE];
    const int tg = blockIdx.x * 256 + threadIdx.x;
    const int d = tg & (DINNER - 1);
    const int bc = tg >> 11;
    const int c = bc & (NC - 1);
    const int b = bc >> 5;

    for (int idx = threadIdx.x; idx < LC * 2 * DSTATE; idx += 256) {
        int ti = idx >> 5, j = idx & 31;
        float v = proj[(size_t)(b * LSEQ + c * LC + ti) * NPROJ + DTRANK + j];
        if (j < DSTATE) Bsh[ti][j] = v;
        else            Csh[ti][j - DSTATE] = v;
    }
    __syncthreads();

    float Av[DSTATE], h[DSTATE];
    size_t o = ((size_t)bc * DINNER + d) * DSTATE;
#pragma unroll
    for (int q = 0; q < 4; q++) {
        float4 hv = *reinterpret_cast<const float4*>(&hstart[o + q * 4]);
        h[4 * q] = hv.x; h[4 * q + 1] = hv.y; h[4 * q + 2] = hv.z; h[4 * q + 3] = hv.w;
    }
#pragma unroll
    for (int s = 0; s < DSTATE; s++)
        Av[s] = -expf(A_log[d * DSTATE + s]);
    const float Dd = Dp[d];

    for (int i = 0; i < LC; i++) {
        size_t base = (size_t)(b * LSEQ + c * LC + i) * DINNER + d;
        float dtv = bf2f(dt[base]);
        float xv = bf2f(xb[base]);
        float szv = bf2f(sz[base]);
        float dx = dtv * xv;
        float Bv[DSTATE], Cv[DSTATE];
        *reinterpret_cast<float4*>(&Bv[0])  = *reinterpret_cast<const float4*>(&Bsh[i][0]);
        *reinterpret_cast<float4*>(&Bv[4])  = *reinterpret_cast<const float4*>(&Bsh[i][4]);
        *reinterpret_cast<float4*>(&Bv[8])  = *reinterpret_cast<const float4*>(&Bsh[i][8]);
        *reinterpret_cast<float4*>(&Bv[12]) = *reinterpret_cast<const float4*>(&Bsh[i][12]);
        *reinterpret_cast<float4*>(&Cv[0])  = *reinterpret_cast<const float4*>(&Csh[i][0]);
        *reinterpret_cast<float4*>(&Cv[4])  = *reinterpret_cast<const float4*>(&Csh[i][4]);
        *reinterpret_cast<float4*>(&Cv[8])  = *reinterpret_cast<const float4*>(&Csh[i][8]);
        *reinterpret_cast<float4*>(&Cv[12]) = *reinterpret_cast<const float4*>(&Csh[i][12]);
        float p = 0.f;
#pragma unroll
        for (int s = 0; s < DSTATE; s++) {
            float dA = __expf(dtv * Av[s]);
            h[s] = fmaf(dA, h[s], dx * Bv[s]);
            p = fmaf(h[s], Cv[s], p);
        }
        ybf[base] = f2bf((p + Dd * xv) * szv);
    }
}

extern "C" void kernel_launch(void* const* d_in, const int* in_sizes, int n_in,
                              void* d_out, int out_size, void* d_ws,
                              size_t ws_size, hipStream_t stream) {
    const float* x = (const float*)d_in[0];
    const float* W_in = (const float*)d_in[1];
    const float* conv_w = (const float*)d_in[2];
    const float* conv_b = (const float*)d_in[3];
    const float* W_xproj = (const float*)d_in[4];
    const float* W_dt = (const float*)d_in[5];
    const float* b_dt = (const float*)d_in[6];
    const float* A_log = (const float*)d_in[7];
    const float* Dp = (const float*)d_in[8];
    const float* W_out = (const float*)d_in[9];
    float* out = (float*)d_out;

    char* ws = (char*)d_ws;
    const size_t MB = 1u << 20;
    float* pp    = (float*)(ws);
    float* aprod = (float*)(ws);
    float* hend  = (float*)(ws + 8 * MB);
    unsigned short* xbpre_bf = (unsigned short*)(ws + 16 * MB);  // 16 MB
    unsigned short* ybf      = (unsigned short*)(ws + 16 * MB);  // 16 MB (after proj_conv)
    unsigned short* sz_bf    = (unsigned short*)(ws + 32 * MB);  // 16 MB
    unsigned short* xb_bf    = (unsigned short*)(ws + 48 * MB);  // 16 MB
    unsigned short* dt_bf    = (unsigned short*)(ws + 64 * MB);  // 16 MB
    float* projbuf           = (float*)(ws + 88 * MB);           // 1.5 MB
    unsigned short* dtin_bf  = (unsigned short*)(ws + 90 * MB);  // 0.5 MB
    unsigned short* xbf      = (unsigned short*)(ws + 91 * MB);  // 8 MB
    unsigned short* WinT     = (unsigned short*)(ws + 99 * MB);  // 8 MB
    unsigned short* WoutT    = (unsigned short*)(ws + 107 * MB); // 4 MB
    unsigned short* WxT      = (unsigned short*)(ws + 111 * MB); // 384 KB
    unsigned short* WdtT     = (unsigned short*)(ws + 112 * MB); // 256 KB

    const int M = BSZ * LSEQ; // 4096
    dim3 blk(256);

    // 0. fused prep
    prep_kernel<<<dim3(4096 + 1024 + 512 + 192 + 128), blk, 0, stream>>>(
        x, W_in, W_out, W_xproj, W_dt, xbf, WinT, WoutT, WxT, WdtT);

    // 1. xz = x @ W_in — 256x128 tile, 512 blocks
    gemm_bm256<1, unsigned short><<<dim3((2 * DINNER) / 128, M / 256), dim3(512),
                                    0, stream>>>(
        xbf, WinT, xbpre_bf, sz_bf, M, 2 * DINNER, DMODEL);

    // 2+3. fused conv + proj split-K
    proj_conv<<<dim3(M / 32, KS), blk, 0, stream>>>(
        xbpre_bf, conv_w, conv_b, WxT, xb_bf, pp);
    proj_reduce<<<dim3((M * NPROJ) / 256), blk, 0, stream>>>(pp, projbuf, dtin_bf);

    // 4. dt = softplus(dt_in @ W_dt + b_dt)
    dt_gemm<<<dim3(M / 32, DINNER / 128), blk, 0, stream>>>(
        dtin_bf, WdtT, b_dt, dt_bf);

    // 5. scan (3 separate passes — r15-proven; cooperative fusion regressed 9x)
    const int nthreads1 = BSZ * NC * DINNER;
    scan_pass1<<<dim3(nthreads1 / 256), blk, 0, stream>>>(
        xb_bf, dt_bf, projbuf, A_log, aprod, hend);
    const int nthreads2 = BSZ * DINNER * DSTATE;
    scan_pass2<<<dim3(nthreads2 / 256), blk, 0, stream>>>(aprod, hend);
    scan_pass3<<<dim3(nthreads1 / 256), blk, 0, stream>>>(
        xb_bf, dt_bf, projbuf, aprod, A_log, Dp, sz_bf, ybf);

    // 6. out = y @ W_out (2-phase 128x64)
    gemm_mfma<64, float><<<dim3(DMODEL / 64, M / 128), blk, 0, stream>>>(
        ybf, WoutT, out, M, DMODEL, DINNER);
}